// Round 1
// baseline (2969.136 us; speedup 1.0000x reference)
//
#include <hip/hip_runtime.h>
#include <math.h>

#define Bn 128
#define Nn 512
#define Cc 7
#define Hh 64
#define Kk 16
#define Rr 2
#define EPSf 1e-5f

// ---------------------------------------------------------------------------
// t1 + t2 fused: h = relu(bn2(W2 @ relu(bn1(W1 @ x))))  per point
// block = 256 threads = 4 points x 64 output channels (group == wave)
// also emits sq[p] = sum_c h[p][c]^2 for the kNN kernel
// ---------------------------------------------------------------------------
__global__ __launch_bounds__(256) void k_t12(
    const float* __restrict__ x,
    const float* __restrict__ w1, const float* __restrict__ g1, const float* __restrict__ b1,
    const float* __restrict__ w2, const float* __restrict__ g2, const float* __restrict__ b2,
    float* __restrict__ h, float* __restrict__ sq)
{
    int t = threadIdx.x;
    int grp = t >> 6, o = t & 63;
    int p = blockIdx.x * 4 + grp;          // p = b*N + n
    int b = p >> 9, n = p & 511;

    __shared__ float h1s[4][64];
    const float inv = rsqrtf(1.0f + EPSf);

    float acc = 0.0f;
#pragma unroll
    for (int c = 0; c < Cc; ++c)
        acc = fmaf(w1[o * Cc + c], x[(b * Cc + c) * Nn + n], acc);
    acc = fmaf(acc, g1[o] * inv, b1[o]);
    acc = fmaxf(acc, 0.0f);
    h1s[grp][o] = acc;
    __syncthreads();

    float a2 = 0.0f;
#pragma unroll 8
    for (int c = 0; c < Hh; ++c)
        a2 = fmaf(w2[o * Hh + c], h1s[grp][c], a2);
    a2 = fmaf(a2, g2[o] * inv, b2[o]);
    a2 = fmaxf(a2, 0.0f);
    h[(size_t)p * Hh + o] = a2;

    float s = a2 * a2;
#pragma unroll
    for (int off = 32; off > 0; off >>= 1) s += __shfl_down(s, off, 64);
    if (o == 0) sq[p] = s;
}

// ---------------------------------------------------------------------------
// kNN: for 8 center points, compute all 512 distances, select 16 smallest
// (tie -> lower index, matching jax.lax.top_k stability).
// block = 256 threads; grid = B * N/8
// ---------------------------------------------------------------------------
__global__ __launch_bounds__(256) void k_knn(
    const float* __restrict__ h, const float* __restrict__ sq, int* __restrict__ idxout)
{
    int b  = blockIdx.x >> 6;              // N/8 = 64 tiles per batch
    int n0 = (blockIdx.x & 63) << 3;
    int t  = threadIdx.x;

    __shared__ float4 ctr4[8 * 16];        // 8 centers x 64 ch
    __shared__ float  dist[8 * 512];
    __shared__ float  sqc[8];

    const float* hb = h + (size_t)b * Nn * Hh;
    float* ctr = (float*)ctr4;
    for (int i = t; i < 8 * Hh; i += 256) ctr[i] = hb[(size_t)n0 * Hh + i];
    if (t < 8) sqc[t] = sq[b * Nn + n0 + t];
    __syncthreads();

#pragma unroll
    for (int pass = 0; pass < 2; ++pass) {
        int m = pass * 256 + t;
        const float4* hv = (const float4*)(hb + (size_t)m * Hh);
        float dj[8];
#pragma unroll
        for (int j = 0; j < 8; ++j) dj[j] = 0.0f;
#pragma unroll
        for (int c4 = 0; c4 < 16; ++c4) {
            float4 v = hv[c4];
#pragma unroll
            for (int j = 0; j < 8; ++j) {
                float4 cv = ctr4[j * 16 + c4];
                dj[j] += v.x * cv.x + v.y * cv.y + v.z * cv.z + v.w * cv.w;
            }
        }
        float sm = sq[b * Nn + m];
#pragma unroll
        for (int j = 0; j < 8; ++j)
            dist[j * 512 + m] = sqc[j] + sm - 2.0f * dj[j];
    }
    __syncthreads();

    // selection: half-wave (32 lanes) per center row
    int hw = t >> 5;                        // 0..7
    int lane = t & 31;
    float* drow = dist + hw * 512;
    int outbase = (b * Nn + n0 + hw) * Kk;
    for (int iter = 0; iter < Kk; ++iter) {
        float bv = INFINITY; int bi = -1;
        for (int m = lane; m < 512; m += 32) {
            float v = drow[m];
            if (v < bv) { bv = v; bi = m; }   // ascending m scan: strict < keeps lowest idx
        }
#pragma unroll
        for (int off = 16; off > 0; off >>= 1) {
            float ov = __shfl_down(bv, off, 32);
            int   oi = __shfl_down(bi, off, 32);
            if (ov < bv || (ov == bv && oi < bi)) { bv = ov; bi = oi; }
        }
        bi = __shfl(bi, 0, 32);
        if (lane == 0) {
            idxout[outbase + iter] = bi;
            drow[bi] = INFINITY;
        }
    }
}

// ---------------------------------------------------------------------------
// EdgeConv: out[p][o] = relu(max_k bn( (Wc-Wd)@hc + Wd@h_nbr_k ))
// block = 256 threads = 4 points x 64 out channels; weights transposed in LDS
// (stride 65 to kill bank conflicts). Emits sq of output for next round.
// ---------------------------------------------------------------------------
__global__ __launch_bounds__(256) void k_edge(
    const float* __restrict__ h, const int* __restrict__ idx,
    const float* __restrict__ w,      // (H, 2H) for this round
    const float* __restrict__ g, const float* __restrict__ bb_,
    float* __restrict__ hout, float* __restrict__ sqout)
{
    __shared__ float wdT [64 * 65];
    __shared__ float wcdT[64 * 65];
    __shared__ float hcS[4][64];
    __shared__ float nbS[4][16][64];

    int t = threadIdx.x;
    for (int i = t; i < Hh * Hh; i += 256) {
        int o = i >> 6, c = i & 63;
        float wc = w[o * 2 * Hh + c];
        float wd = w[o * 2 * Hh + Hh + c];
        wdT [c * 65 + o] = wd;
        wcdT[c * 65 + o] = wc - wd;
    }

    int grp = t >> 6, o = t & 63;
    int p0 = blockIdx.x * 4;
    int p  = p0 + grp;
    int b  = p0 >> 9;                      // all 4 points share the batch

    hcS[grp][o] = h[(size_t)p * Hh + o];

    for (int q = 0; q < 16; ++q) {
        int pair = q * 4 + grp;            // 0..63 -> (gi, k)
        int gi = pair >> 4, k = pair & 15;
        int j = idx[(p0 + gi) * Kk + k];
        nbS[gi][k][o] = h[((size_t)b * Nn + j) * Hh + o];
    }
    __syncthreads();

    const float inv = rsqrtf(1.0f + EPSf);
    float sc = g[o] * inv, bo = bb_[o];

    float base = 0.0f;
#pragma unroll 8
    for (int c = 0; c < Hh; ++c)
        base = fmaf(wcdT[c * 65 + o], hcS[grp][c], base);

    float vmax = -INFINITY;
    for (int k = 0; k < Kk; ++k) {
        float nb = 0.0f;
#pragma unroll 8
        for (int c = 0; c < Hh; ++c)
            nb = fmaf(wdT[c * 65 + o], nbS[grp][k][c], nb);
        vmax = fmaxf(vmax, fmaf(base + nb, sc, bo));   // bn per-k, then max
    }
    float res = fmaxf(vmax, 0.0f);                     // relu (monotone, after max)
    hout[(size_t)p * Hh + o] = res;

    float s = res * res;
#pragma unroll
    for (int off = 32; off > 0; off >>= 1) s += __shfl_down(s, off, 64);
    if (o == 0) sqout[p] = s;
}

// ---------------------------------------------------------------------------
// head: logits[p] = w_s2 @ relu(bn(W_s1 @ h[p])) + b_s2
// ---------------------------------------------------------------------------
__global__ __launch_bounds__(256) void k_head(
    const float* __restrict__ h,
    const float* __restrict__ w1, const float* __restrict__ g1, const float* __restrict__ b1,
    const float* __restrict__ w2, const float* __restrict__ b2,
    float* __restrict__ out)
{
    __shared__ float hcS[4][64];
    int t = threadIdx.x;
    int grp = t >> 6, o = t & 63;
    int p = blockIdx.x * 4 + grp;

    hcS[grp][o] = h[(size_t)p * Hh + o];
    __syncthreads();

    const float inv = rsqrtf(1.0f + EPSf);
    float acc = 0.0f;
#pragma unroll 8
    for (int c = 0; c < Hh; ++c)
        acc = fmaf(w1[o * Hh + c], hcS[grp][c], acc);
    acc = fmaxf(fmaf(acc, g1[o] * inv, b1[o]), 0.0f);

    float v = acc * w2[o];
#pragma unroll
    for (int off = 32; off > 0; off >>= 1) v += __shfl_down(v, off, 64);
    if (o == 0) out[p] = v + b2[0];
}

// ---------------------------------------------------------------------------
extern "C" void kernel_launch(void* const* d_in, const int* in_sizes, int n_in,
                              void* d_out, int out_size, void* d_ws, size_t ws_size,
                              hipStream_t stream)
{
    const float* x    = (const float*)d_in[0];
    const float* w_t1 = (const float*)d_in[1];
    const float* g_t1 = (const float*)d_in[2];
    const float* b_t1 = (const float*)d_in[3];
    const float* w_t2 = (const float*)d_in[4];
    const float* g_t2 = (const float*)d_in[5];
    const float* b_t2 = (const float*)d_in[6];
    const float* w_nb = (const float*)d_in[7];
    const float* g_nb = (const float*)d_in[8];
    const float* b_nb = (const float*)d_in[9];
    const float* w_s1 = (const float*)d_in[10];
    const float* g_s1 = (const float*)d_in[11];
    const float* b_s1 = (const float*)d_in[12];
    const float* w_s2 = (const float*)d_in[13];
    const float* b_s2 = (const float*)d_in[14];
    float* out = (float*)d_out;

    float* hA  = (float*)d_ws;
    float* hB  = hA + (size_t)Bn * Nn * Hh;
    float* sq  = hB + (size_t)Bn * Nn * Hh;
    int*   idx = (int*)(sq + (size_t)Bn * Nn);

    k_t12<<<Bn * Nn / 4, 256, 0, stream>>>(x, w_t1, g_t1, b_t1, w_t2, g_t2, b_t2, hA, sq);

    const float* hin = hA;
    float* hout = hB;
    for (int r = 0; r < Rr; ++r) {
        k_knn<<<Bn * (Nn / 8), 256, 0, stream>>>(hin, sq, idx);
        k_edge<<<Bn * Nn / 4, 256, 0, stream>>>(hin, idx,
            w_nb + (size_t)r * Hh * 2 * Hh, g_nb + r * Hh, b_nb + r * Hh, hout, sq);
        const float* tmp = hout; hout = (float*)hin; hin = tmp;
    }
    k_head<<<Bn * Nn / 4, 256, 0, stream>>>(hin, w_s1, g_s1, b_s1, w_s2, b_s2, out);
}

// Round 2
// 1417.860 us; speedup vs baseline: 2.0941x; 2.0941x over previous
//
#include <hip/hip_runtime.h>
#include <math.h>

#define Bn 128
#define Nn 512
#define Cc 7
#define Hh 64
#define Kk 16
#define Rr 2
#define EPSf 1e-5f

// ---------------------------------------------------------------------------
// t1 + t2 fused (unchanged from round 1 — bit-identical h)
// ---------------------------------------------------------------------------
__global__ __launch_bounds__(256) void k_t12(
    const float* __restrict__ x,
    const float* __restrict__ w1, const float* __restrict__ g1, const float* __restrict__ b1,
    const float* __restrict__ w2, const float* __restrict__ g2, const float* __restrict__ b2,
    float* __restrict__ h, float* __restrict__ sq)
{
    int t = threadIdx.x;
    int grp = t >> 6, o = t & 63;
    int p = blockIdx.x * 4 + grp;
    int b = p >> 9, n = p & 511;

    __shared__ float h1s[4][64];
    const float inv = rsqrtf(1.0f + EPSf);

    float acc = 0.0f;
#pragma unroll
    for (int c = 0; c < Cc; ++c)
        acc = fmaf(w1[o * Cc + c], x[(b * Cc + c) * Nn + n], acc);
    acc = fmaf(acc, g1[o] * inv, b1[o]);
    acc = fmaxf(acc, 0.0f);
    h1s[grp][o] = acc;
    __syncthreads();

    float a2 = 0.0f;
#pragma unroll 8
    for (int c = 0; c < Hh; ++c)
        a2 = fmaf(w2[o * Hh + c], h1s[grp][c], a2);
    a2 = fmaf(a2, g2[o] * inv, b2[o]);
    a2 = fmaxf(a2, 0.0f);
    h[(size_t)p * Hh + o] = a2;

    float s = a2 * a2;
#pragma unroll
    for (int off = 32; off > 0; off >>= 1) s += __shfl_down(s, off, 64);
    if (o == 0) sq[p] = s;
}

// ---------------------------------------------------------------------------
// kNN fused: distance phase identical accumulation to round 1, then packed
// u32 keys in LDS; selection = per-wave register tournament.
// Key = order-preserving uint of dist; lane-major candidate layout so
// lowest ballot lane == lowest index (exact lax.top_k tie semantics).
// ---------------------------------------------------------------------------
__global__ __launch_bounds__(256) void k_knn(
    const float* __restrict__ h, const float* __restrict__ sq, int* __restrict__ idxout)
{
    int bidx = blockIdx.x;
    int b  = bidx >> 6;
    int n0 = (bidx & 63) << 3;
    int t  = threadIdx.x;

    __shared__ float4 ctr4[8 * 16];
    __shared__ unsigned int keysLDS[8 * 512];
    __shared__ float sqc[8];

    const float* hb = h + (size_t)b * Nn * Hh;
    float* ctr = (float*)ctr4;
    for (int i = t; i < 8 * Hh; i += 256) ctr[i] = hb[(size_t)n0 * Hh + i];
    if (t < 8) sqc[t] = sq[b * Nn + n0 + t];
    __syncthreads();

#pragma unroll
    for (int pass = 0; pass < 2; ++pass) {
        int m = pass * 256 + t;
        const float4* hv = (const float4*)(hb + (size_t)m * Hh);
        float dj[8];
#pragma unroll
        for (int j = 0; j < 8; ++j) dj[j] = 0.0f;
#pragma unroll
        for (int c4 = 0; c4 < 16; ++c4) {
            float4 v = hv[c4];
#pragma unroll
            for (int j = 0; j < 8; ++j) {
                float4 cv = ctr4[j * 16 + c4];
                dj[j] += v.x * cv.x + v.y * cv.y + v.z * cv.z + v.w * cv.w;
            }
        }
        float sm = sq[b * Nn + m];
#pragma unroll
        for (int j = 0; j < 8; ++j) {
            float d = sqc[j] + sm - 2.0f * dj[j];
            unsigned int u = __float_as_uint(d);
            u = ((int)u < 0) ? ~u : (u | 0x80000000u);
            keysLDS[j * 512 + m] = u;
        }
    }
    __syncthreads();

    // selection: wave w handles points j = 2w, 2w+1
    int wvid = t >> 6, lane = t & 63;
    for (int s = 0; s < 2; ++s) {
        int jj = wvid * 2 + s;
        unsigned int kk[8];
        int rr[8];
        const uint4* kp = (const uint4*)&keysLDS[jj * 512 + (lane << 3)];
        uint4 A = kp[0], Bq = kp[1];
        kk[0] = A.x;  kk[1] = A.y;  kk[2] = A.z;  kk[3] = A.w;
        kk[4] = Bq.x; kk[5] = Bq.y; kk[6] = Bq.z; kk[7] = Bq.w;
#pragma unroll
        for (int q = 0; q < 8; ++q) rr[q] = q;

#define CE(i, j_) { \
        bool sw = (kk[i] > kk[j_]) || (kk[i] == kk[j_] && rr[i] > rr[j_]); \
        unsigned int tk = sw ? kk[i] : kk[j_]; kk[i] = sw ? kk[j_] : kk[i]; kk[j_] = tk; \
        int tr = sw ? rr[i] : rr[j_]; rr[i] = sw ? rr[j_] : rr[i]; rr[j_] = tr; }
        // Batcher odd-even mergesort, 8 elements, 19 CEs
        CE(0,1) CE(2,3) CE(4,5) CE(6,7)
        CE(0,2) CE(1,3) CE(4,6) CE(5,7)
        CE(1,2) CE(5,6)
        CE(0,4) CE(1,5) CE(2,6) CE(3,7)
        CE(2,4) CE(3,5)
        CE(1,2) CE(3,4) CE(5,6)
#undef CE

        int outbase = (b * Nn + n0 + jj) * Kk;
        for (int iter = 0; iter < Kk; ++iter) {
            unsigned int m = kk[0];
#pragma unroll
            for (int sh = 1; sh < 64; sh <<= 1) {
                unsigned int o2 = __shfl_xor(m, sh, 64);
                m = (o2 < m) ? o2 : m;
            }
            bool have = (kk[0] == m);
            unsigned long long bal = __ballot(have);
            int winner = __ffsll(bal) - 1;
            if (lane == winner) {
                idxout[outbase + iter] = (lane << 3) + rr[0];
#pragma unroll
                for (int q = 0; q < 7; ++q) { kk[q] = kk[q + 1]; rr[q] = rr[q + 1]; }
                kk[7] = 0xFFFFFFFFu;
            }
        }
    }
}

// ---------------------------------------------------------------------------
// EdgeConv: row-major W in LDS (stride 68 -> clean 8-phase ds_read_b128),
// float4 broadcast neighbor reads, 17 independent accumulator chains.
// Accumulation order per output is bit-identical to round 1 (chained fmaf,
// c ascending; bn-before-max, k ascending).
// ---------------------------------------------------------------------------
__global__ __launch_bounds__(256) void k_edge(
    const float* __restrict__ h, const int* __restrict__ idx,
    const float* __restrict__ w,
    const float* __restrict__ g, const float* __restrict__ bb_,
    float* __restrict__ hout, float* __restrict__ sqout)
{
    __shared__ float wdR [64 * 68];
    __shared__ float wcdR[64 * 68];
    __shared__ float hcS[4][64];
    __shared__ float nbS[4][16][64];

    int t = threadIdx.x;
    for (int i = t; i < Hh * Hh; i += 256) {
        int o = i >> 6, c = i & 63;
        float wc = w[o * 2 * Hh + c];
        float wd = w[o * 2 * Hh + Hh + c];
        wdR [o * 68 + c] = wd;
        wcdR[o * 68 + c] = wc - wd;
    }

    int grp = t >> 6, o = t & 63;
    int p0 = blockIdx.x * 4;
    int p  = p0 + grp;
    int b  = p0 >> 9;

    hcS[grp][o] = h[(size_t)p * Hh + o];

#pragma unroll
    for (int q = 0; q < 16; ++q) {
        int pair = q * 4 + grp;
        int gi = pair >> 4, k = pair & 15;
        int j = idx[(p0 + gi) * Kk + k];
        nbS[gi][k][o] = h[((size_t)b * Nn + j) * Hh + o];
    }
    __syncthreads();

    const float4* wd4p  = (const float4*)&wdR [o * 68];
    const float4* wcd4p = (const float4*)&wcdR[o * 68];
    const float4* hc4p  = (const float4*)&hcS[grp][0];
    const float4* nb4p  = (const float4*)&nbS[grp][0][0];

    float base = 0.0f;
    float vk[16];
#pragma unroll
    for (int k = 0; k < 16; ++k) vk[k] = 0.0f;

    for (int c4 = 0; c4 < 16; ++c4) {
        float4 wd4  = wd4p[c4];
        float4 wcd4 = wcd4p[c4];
        float4 hc4  = hc4p[c4];
        base = fmaf(wcd4.x, hc4.x, base);
        base = fmaf(wcd4.y, hc4.y, base);
        base = fmaf(wcd4.z, hc4.z, base);
        base = fmaf(wcd4.w, hc4.w, base);
#pragma unroll
        for (int k = 0; k < 16; ++k) {
            float4 nb4 = nb4p[k * 16 + c4];
            float a = vk[k];
            a = fmaf(wd4.x, nb4.x, a);
            a = fmaf(wd4.y, nb4.y, a);
            a = fmaf(wd4.z, nb4.z, a);
            a = fmaf(wd4.w, nb4.w, a);
            vk[k] = a;
        }
    }

    const float inv = rsqrtf(1.0f + EPSf);
    float sc = g[o] * inv, bo = bb_[o];
    float vmax = -INFINITY;
#pragma unroll
    for (int k = 0; k < 16; ++k)
        vmax = fmaxf(vmax, fmaf(base + vk[k], sc, bo));

    float res = fmaxf(vmax, 0.0f);
    hout[(size_t)p * Hh + o] = res;

    float s = res * res;
#pragma unroll
    for (int off = 32; off > 0; off >>= 1) s += __shfl_down(s, off, 64);
    if (o == 0) sqout[p] = s;
}

// ---------------------------------------------------------------------------
// head (unchanged)
// ---------------------------------------------------------------------------
__global__ __launch_bounds__(256) void k_head(
    const float* __restrict__ h,
    const float* __restrict__ w1, const float* __restrict__ g1, const float* __restrict__ b1,
    const float* __restrict__ w2, const float* __restrict__ b2,
    float* __restrict__ out)
{
    __shared__ float hcS[4][64];
    int t = threadIdx.x;
    int grp = t >> 6, o = t & 63;
    int p = blockIdx.x * 4 + grp;

    hcS[grp][o] = h[(size_t)p * Hh + o];
    __syncthreads();

    const float inv = rsqrtf(1.0f + EPSf);
    float acc = 0.0f;
#pragma unroll 8
    for (int c = 0; c < Hh; ++c)
        acc = fmaf(w1[o * Hh + c], hcS[grp][c], acc);
    acc = fmaxf(fmaf(acc, g1[o] * inv, b1[o]), 0.0f);

    float v = acc * w2[o];
#pragma unroll
    for (int off = 32; off > 0; off >>= 1) v += __shfl_down(v, off, 64);
    if (o == 0) out[p] = v + b2[0];
}

// ---------------------------------------------------------------------------
extern "C" void kernel_launch(void* const* d_in, const int* in_sizes, int n_in,
                              void* d_out, int out_size, void* d_ws, size_t ws_size,
                              hipStream_t stream)
{
    const float* x    = (const float*)d_in[0];
    const float* w_t1 = (const float*)d_in[1];
    const float* g_t1 = (const float*)d_in[2];
    const float* b_t1 = (const float*)d_in[3];
    const float* w_t2 = (const float*)d_in[4];
    const float* g_t2 = (const float*)d_in[5];
    const float* b_t2 = (const float*)d_in[6];
    const float* w_nb = (const float*)d_in[7];
    const float* g_nb = (const float*)d_in[8];
    const float* b_nb = (const float*)d_in[9];
    const float* w_s1 = (const float*)d_in[10];
    const float* g_s1 = (const float*)d_in[11];
    const float* b_s1 = (const float*)d_in[12];
    const float* w_s2 = (const float*)d_in[13];
    const float* b_s2 = (const float*)d_in[14];
    float* out = (float*)d_out;

    float* hA  = (float*)d_ws;
    float* hB  = hA + (size_t)Bn * Nn * Hh;
    float* sq  = hB + (size_t)Bn * Nn * Hh;
    int*   idx = (int*)(sq + (size_t)Bn * Nn);

    k_t12<<<Bn * Nn / 4, 256, 0, stream>>>(x, w_t1, g_t1, b_t1, w_t2, g_t2, b_t2, hA, sq);

    const float* hin = hA;
    float* hout = hB;
    for (int r = 0; r < Rr; ++r) {
        k_knn<<<Bn * (Nn / 8), 256, 0, stream>>>(hin, sq, idx);
        k_edge<<<Bn * Nn / 4, 256, 0, stream>>>(hin, idx,
            w_nb + (size_t)r * Hh * 2 * Hh, g_nb + r * Hh, b_nb + r * Hh, hout, sq);
        const float* tmp = hout; hout = (float*)hin; hin = tmp;
    }
    k_head<<<Bn * Nn / 4, 256, 0, stream>>>(hin, w_s1, g_s1, b_s1, w_s2, b_s2, out);
}

// Round 3
// 1042.726 us; speedup vs baseline: 2.8475x; 1.3598x over previous
//
#include <hip/hip_runtime.h>
#include <math.h>

#define Bn 128
#define Nn 512
#define Cc 7
#define Hh 64
#define Kk 16
#define Rr 2
#define EPSf 1e-5f

// ---------------------------------------------------------------------------
// t1 + t2 fused (unchanged — bit-identical h)
// ---------------------------------------------------------------------------
__global__ __launch_bounds__(256) void k_t12(
    const float* __restrict__ x,
    const float* __restrict__ w1, const float* __restrict__ g1, const float* __restrict__ b1,
    const float* __restrict__ w2, const float* __restrict__ g2, const float* __restrict__ b2,
    float* __restrict__ h, float* __restrict__ sq)
{
    int t = threadIdx.x;
    int grp = t >> 6, o = t & 63;
    int p = blockIdx.x * 4 + grp;
    int b = p >> 9, n = p & 511;

    __shared__ float h1s[4][64];
    const float inv = rsqrtf(1.0f + EPSf);

    float acc = 0.0f;
#pragma unroll
    for (int c = 0; c < Cc; ++c)
        acc = fmaf(w1[o * Cc + c], x[(b * Cc + c) * Nn + n], acc);
    acc = fmaf(acc, g1[o] * inv, b1[o]);
    acc = fmaxf(acc, 0.0f);
    h1s[grp][o] = acc;
    __syncthreads();

    float a2 = 0.0f;
#pragma unroll 8
    for (int c = 0; c < Hh; ++c)
        a2 = fmaf(w2[o * Hh + c], h1s[grp][c], a2);
    a2 = fmaf(a2, g2[o] * inv, b2[o]);
    a2 = fmaxf(a2, 0.0f);
    h[(size_t)p * Hh + o] = a2;

    float s = a2 * a2;
#pragma unroll
    for (int off = 32; off > 0; off >>= 1) s += __shfl_down(s, off, 64);
    if (o == 0) sq[p] = s;
}

// ---------------------------------------------------------------------------
// kNN: distance phase 2 points/thread (ctr LDS reads amortized 2x);
// selection: both of a wave's points processed concurrently (2 interleaved
// butterfly chains). Keys/ordering bit-identical to round 2.
// ---------------------------------------------------------------------------
__global__ __launch_bounds__(256) void k_knn(
    const float* __restrict__ h, const float* __restrict__ sq, int* __restrict__ idxout)
{
    int bidx = blockIdx.x;
    int b  = bidx >> 6;
    int n0 = (bidx & 63) << 3;
    int t  = threadIdx.x;

    __shared__ float4 ctr4[8 * 16];
    __shared__ unsigned int keysLDS[8 * 512];
    __shared__ float sqc[8];

    const float* hb = h + (size_t)b * Nn * Hh;
    float* ctr = (float*)ctr4;
    for (int i = t; i < 8 * Hh; i += 256) ctr[i] = hb[(size_t)n0 * Hh + i];
    if (t < 8) sqc[t] = sq[b * Nn + n0 + t];
    __syncthreads();

    {
        int m  = t;
        int m2 = t + 256;
        const float4* hv  = (const float4*)(hb + (size_t)m  * Hh);
        const float4* hv2 = (const float4*)(hb + (size_t)m2 * Hh);
        float dj[8], ej[8];
#pragma unroll
        for (int j = 0; j < 8; ++j) { dj[j] = 0.0f; ej[j] = 0.0f; }
#pragma unroll
        for (int c4 = 0; c4 < 16; ++c4) {
            float4 v  = hv[c4];
            float4 v2 = hv2[c4];
#pragma unroll
            for (int j = 0; j < 8; ++j) {
                float4 cv = ctr4[j * 16 + c4];
                dj[j] += v.x  * cv.x + v.y  * cv.y + v.z  * cv.z + v.w  * cv.w;
                ej[j] += v2.x * cv.x + v2.y * cv.y + v2.z * cv.z + v2.w * cv.w;
            }
        }
        float sm  = sq[b * Nn + m];
        float sm2 = sq[b * Nn + m2];
#pragma unroll
        for (int j = 0; j < 8; ++j) {
            float d = sqc[j] + sm - 2.0f * dj[j];
            unsigned int u = __float_as_uint(d);
            u = ((int)u < 0) ? ~u : (u | 0x80000000u);
            keysLDS[j * 512 + m] = u;

            float d2 = sqc[j] + sm2 - 2.0f * ej[j];
            unsigned int u2 = __float_as_uint(d2);
            u2 = ((int)u2 < 0) ? ~u2 : (u2 | 0x80000000u);
            keysLDS[j * 512 + m2] = u2;
        }
    }
    __syncthreads();

    // selection: wave w handles points j0=2w, j1=2w+1 CONCURRENTLY
    int wvid = t >> 6, lane = t & 63;
    int j0 = wvid * 2, j1 = wvid * 2 + 1;

    unsigned int k0[8], k1[8];
    int r0[8], r1[8];
    {
        const uint4* kp0 = (const uint4*)&keysLDS[j0 * 512 + (lane << 3)];
        const uint4* kp1 = (const uint4*)&keysLDS[j1 * 512 + (lane << 3)];
        uint4 A = kp0[0], Bq = kp0[1];
        k0[0] = A.x;  k0[1] = A.y;  k0[2] = A.z;  k0[3] = A.w;
        k0[4] = Bq.x; k0[5] = Bq.y; k0[6] = Bq.z; k0[7] = Bq.w;
        uint4 C = kp1[0], D = kp1[1];
        k1[0] = C.x;  k1[1] = C.y;  k1[2] = C.z;  k1[3] = C.w;
        k1[4] = D.x;  k1[5] = D.y;  k1[6] = D.z;  k1[7] = D.w;
    }
#pragma unroll
    for (int q = 0; q < 8; ++q) { r0[q] = q; r1[q] = q; }

#define CE(kk, rr, i, j_) { \
    bool sw = (kk[i] > kk[j_]) || (kk[i] == kk[j_] && rr[i] > rr[j_]); \
    unsigned int tk = sw ? kk[i] : kk[j_]; kk[i] = sw ? kk[j_] : kk[i]; kk[j_] = tk; \
    int tr = sw ? rr[i] : rr[j_]; rr[i] = sw ? rr[j_] : rr[i]; rr[j_] = tr; }
#define SORT8(kk, rr) \
    CE(kk,rr,0,1) CE(kk,rr,2,3) CE(kk,rr,4,5) CE(kk,rr,6,7) \
    CE(kk,rr,0,2) CE(kk,rr,1,3) CE(kk,rr,4,6) CE(kk,rr,5,7) \
    CE(kk,rr,1,2) CE(kk,rr,5,6) \
    CE(kk,rr,0,4) CE(kk,rr,1,5) CE(kk,rr,2,6) CE(kk,rr,3,7) \
    CE(kk,rr,2,4) CE(kk,rr,3,5) \
    CE(kk,rr,1,2) CE(kk,rr,3,4) CE(kk,rr,5,6)

    SORT8(k0, r0)
    SORT8(k1, r1)
#undef SORT8
#undef CE

    int outbase0 = (b * Nn + n0 + j0) * Kk;
    int outbase1 = (b * Nn + n0 + j1) * Kk;

    for (int iter = 0; iter < Kk; ++iter) {
        unsigned int m0 = k0[0];
        unsigned int m1 = k1[0];
#pragma unroll
        for (int sh = 1; sh < 64; sh <<= 1) {
            unsigned int o0 = __shfl_xor(m0, sh, 64);
            unsigned int o1 = __shfl_xor(m1, sh, 64);
            m0 = (o0 < m0) ? o0 : m0;
            m1 = (o1 < m1) ? o1 : m1;
        }
        unsigned long long bal0 = __ballot(k0[0] == m0);
        unsigned long long bal1 = __ballot(k1[0] == m1);
        int w0 = __ffsll(bal0) - 1;
        int w1 = __ffsll(bal1) - 1;
        if (lane == w0) {
            idxout[outbase0 + iter] = (lane << 3) + r0[0];
#pragma unroll
            for (int q = 0; q < 7; ++q) { k0[q] = k0[q + 1]; r0[q] = r0[q + 1]; }
            k0[7] = 0xFFFFFFFFu;
        }
        if (lane == w1) {
            idxout[outbase1 + iter] = (lane << 3) + r1[0];
#pragma unroll
            for (int q = 0; q < 7; ++q) { k1[q] = k1[q + 1]; r1[q] = r1[q + 1]; }
            k1[7] = 0xFFFFFFFFu;
        }
    }
}

// ---------------------------------------------------------------------------
// EdgeConv: vectorized float4 staging for W, neighbors, and centers;
// compute loop bit-identical to round 2.
// ---------------------------------------------------------------------------
__global__ __launch_bounds__(256) void k_edge(
    const float* __restrict__ h, const int* __restrict__ idx,
    const float* __restrict__ w,
    const float* __restrict__ g, const float* __restrict__ bb_,
    float* __restrict__ hout, float* __restrict__ sqout)
{
    __shared__ float wdR [64 * 68];
    __shared__ float wcdR[64 * 68];
    __shared__ float hcS[4][64];
    __shared__ float nbS[4][16][64];
    __shared__ int   idxS[64];

    int t = threadIdx.x;
    int p0 = blockIdx.x * 4;
    int b  = p0 >> 9;

    // phase 1: stage idx (64 contiguous ints) and centers (4x64 floats)
    if (t < 64) {
        idxS[t] = idx[p0 * Kk + t];
        int gi = t >> 4, c4 = t & 15;
        ((float4*)&hcS[0][0])[t] = ((const float4*)(h + (size_t)(p0 + gi) * Hh))[c4];
    }
    // W staging: 64 rows x 16 float4 x 2 halves; 4 iters x 256 threads
#pragma unroll
    for (int it = 0; it < 4; ++it) {
        int flat = it * 256 + t;           // 0..1023
        int o = flat >> 4, c4 = flat & 15;
        float4 wc4 = ((const float4*)(w + (size_t)o * 2 * Hh))[c4];
        float4 wd4 = ((const float4*)(w + (size_t)o * 2 * Hh + Hh))[c4];
        ((float4*)&wdR[o * 68])[c4] = wd4;
        float4 wcd; wcd.x = wc4.x - wd4.x; wcd.y = wc4.y - wd4.y;
        wcd.z = wc4.z - wd4.z; wcd.w = wc4.w - wd4.w;
        ((float4*)&wcdR[o * 68])[c4] = wcd;
    }
    __syncthreads();

    // phase 2: stage neighbors (64 rows x 16 float4), idx from LDS
#pragma unroll
    for (int it = 0; it < 4; ++it) {
        int flat = it * 256 + t;           // 0..1023
        int row = flat >> 4, c4 = flat & 15;
        int j = idxS[row];
        int gi = row >> 4, k = row & 15;
        ((float4*)&nbS[gi][k][0])[c4] =
            ((const float4*)(h + ((size_t)b * Nn + j) * Hh))[c4];
    }
    __syncthreads();

    int grp = t >> 6, o = t & 63;
    int p = p0 + grp;

    const float4* wd4p  = (const float4*)&wdR [o * 68];
    const float4* wcd4p = (const float4*)&wcdR[o * 68];
    const float4* hc4p  = (const float4*)&hcS[grp][0];
    const float4* nb4p  = (const float4*)&nbS[grp][0][0];

    float base = 0.0f;
    float vk[16];
#pragma unroll
    for (int k = 0; k < 16; ++k) vk[k] = 0.0f;

    for (int c4 = 0; c4 < 16; ++c4) {
        float4 wd4  = wd4p[c4];
        float4 wcd4 = wcd4p[c4];
        float4 hc4  = hc4p[c4];
        base = fmaf(wcd4.x, hc4.x, base);
        base = fmaf(wcd4.y, hc4.y, base);
        base = fmaf(wcd4.z, hc4.z, base);
        base = fmaf(wcd4.w, hc4.w, base);
#pragma unroll
        for (int k = 0; k < 16; ++k) {
            float4 nb4 = nb4p[k * 16 + c4];
            float a = vk[k];
            a = fmaf(wd4.x, nb4.x, a);
            a = fmaf(wd4.y, nb4.y, a);
            a = fmaf(wd4.z, nb4.z, a);
            a = fmaf(wd4.w, nb4.w, a);
            vk[k] = a;
        }
    }

    const float inv = rsqrtf(1.0f + EPSf);
    float sc = g[o] * inv, bo = bb_[o];
    float vmax = -INFINITY;
#pragma unroll
    for (int k = 0; k < 16; ++k)
        vmax = fmaxf(vmax, fmaf(base + vk[k], sc, bo));

    float res = fmaxf(vmax, 0.0f);
    hout[(size_t)p * Hh + o] = res;

    float s = res * res;
#pragma unroll
    for (int off = 32; off > 0; off >>= 1) s += __shfl_down(s, off, 64);
    if (o == 0) sqout[p] = s;
}

// ---------------------------------------------------------------------------
// head (unchanged)
// ---------------------------------------------------------------------------
__global__ __launch_bounds__(256) void k_head(
    const float* __restrict__ h,
    const float* __restrict__ w1, const float* __restrict__ g1, const float* __restrict__ b1,
    const float* __restrict__ w2, const float* __restrict__ b2,
    float* __restrict__ out)
{
    __shared__ float hcS[4][64];
    int t = threadIdx.x;
    int grp = t >> 6, o = t & 63;
    int p = blockIdx.x * 4 + grp;

    hcS[grp][o] = h[(size_t)p * Hh + o];
    __syncthreads();

    const float inv = rsqrtf(1.0f + EPSf);
    float acc = 0.0f;
#pragma unroll 8
    for (int c = 0; c < Hh; ++c)
        acc = fmaf(w1[o * Hh + c], hcS[grp][c], acc);
    acc = fmaxf(fmaf(acc, g1[o] * inv, b1[o]), 0.0f);

    float v = acc * w2[o];
#pragma unroll
    for (int off = 32; off > 0; off >>= 1) v += __shfl_down(v, off, 64);
    if (o == 0) out[p] = v + b2[0];
}

// ---------------------------------------------------------------------------
extern "C" void kernel_launch(void* const* d_in, const int* in_sizes, int n_in,
                              void* d_out, int out_size, void* d_ws, size_t ws_size,
                              hipStream_t stream)
{
    const float* x    = (const float*)d_in[0];
    const float* w_t1 = (const float*)d_in[1];
    const float* g_t1 = (const float*)d_in[2];
    const float* b_t1 = (const float*)d_in[3];
    const float* w_t2 = (const float*)d_in[4];
    const float* g_t2 = (const float*)d_in[5];
    const float* b_t2 = (const float*)d_in[6];
    const float* w_nb = (const float*)d_in[7];
    const float* g_nb = (const float*)d_in[8];
    const float* b_nb = (const float*)d_in[9];
    const float* w_s1 = (const float*)d_in[10];
    const float* g_s1 = (const float*)d_in[11];
    const float* b_s1 = (const float*)d_in[12];
    const float* w_s2 = (const float*)d_in[13];
    const float* b_s2 = (const float*)d_in[14];
    float* out = (float*)d_out;

    float* hA  = (float*)d_ws;
    float* hB  = hA + (size_t)Bn * Nn * Hh;
    float* sq  = hB + (size_t)Bn * Nn * Hh;
    int*   idx = (int*)(sq + (size_t)Bn * Nn);

    k_t12<<<Bn * Nn / 4, 256, 0, stream>>>(x, w_t1, g_t1, b_t1, w_t2, g_t2, b_t2, hA, sq);

    const float* hin = hA;
    float* hout = hB;
    for (int r = 0; r < Rr; ++r) {
        k_knn<<<Bn * (Nn / 8), 256, 0, stream>>>(hin, sq, idx);
        k_edge<<<Bn * Nn / 4, 256, 0, stream>>>(hin, idx,
            w_nb + (size_t)r * Hh * 2 * Hh, g_nb + r * Hh, b_nb + r * Hh, hout, sq);
        const float* tmp = hout; hout = (float*)hin; hin = tmp;
    }
    k_head<<<Bn * Nn / 4, 256, 0, stream>>>(hin, w_s1, g_s1, b_s1, w_s2, b_s2, out);
}

// Round 4
// 921.277 us; speedup vs baseline: 3.2228x; 1.1318x over previous
//
#include <hip/hip_runtime.h>
#include <math.h>

#define Bn 128
#define Nn 512
#define Cc 7
#define Hh 64
#define Kk 16
#define Rr 2
#define EPSf 1e-5f

typedef __attribute__((ext_vector_type(8))) short bf16x8;
typedef __attribute__((ext_vector_type(4))) float f32x4;

// exact truncation split: a = hi + mid + lo + r, |r| <= 2^-24 |a|
__device__ __forceinline__ void split3(float a, short &hs, short &ms, short &ls) {
    unsigned u  = __float_as_uint(a);
    unsigned hu = u & 0xFFFF0000u;
    float r1 = a - __uint_as_float(hu);
    unsigned mu = __float_as_uint(r1) & 0xFFFF0000u;
    float r2 = r1 - __uint_as_float(mu);
    unsigned lu = __float_as_uint(r2) & 0xFFFF0000u;
    hs = (short)(hu >> 16); ms = (short)(mu >> 16); ls = (short)(lu >> 16);
}
__device__ __forceinline__ unsigned pk(short a, short b) {
    return ((unsigned)(unsigned short)a) | (((unsigned)(unsigned short)b) << 16);
}

// ---------------------------------------------------------------------------
// t1 + t2 fused (unchanged — bit-identical h)
// ---------------------------------------------------------------------------
__global__ __launch_bounds__(256) void k_t12(
    const float* __restrict__ x,
    const float* __restrict__ w1, const float* __restrict__ g1, const float* __restrict__ b1,
    const float* __restrict__ w2, const float* __restrict__ g2, const float* __restrict__ b2,
    float* __restrict__ h, float* __restrict__ sq)
{
    int t = threadIdx.x;
    int grp = t >> 6, o = t & 63;
    int p = blockIdx.x * 4 + grp;
    int b = p >> 9, n = p & 511;

    __shared__ float h1s[4][64];
    const float inv = rsqrtf(1.0f + EPSf);

    float acc = 0.0f;
#pragma unroll
    for (int c = 0; c < Cc; ++c)
        acc = fmaf(w1[o * Cc + c], x[(b * Cc + c) * Nn + n], acc);
    acc = fmaf(acc, g1[o] * inv, b1[o]);
    acc = fmaxf(acc, 0.0f);
    h1s[grp][o] = acc;
    __syncthreads();

    float a2 = 0.0f;
#pragma unroll 8
    for (int c = 0; c < Hh; ++c)
        a2 = fmaf(w2[o * Hh + c], h1s[grp][c], a2);
    a2 = fmaf(a2, g2[o] * inv, b2[o]);
    a2 = fmaxf(a2, 0.0f);
    h[(size_t)p * Hh + o] = a2;

    float s = a2 * a2;
#pragma unroll
    for (int off = 32; off > 0; off >>= 1) s += __shfl_down(s, off, 64);
    if (o == 0) sq[p] = s;
}

// ---------------------------------------------------------------------------
// kNN (unchanged from round 3 — bit-identical indices)
// ---------------------------------------------------------------------------
__global__ __launch_bounds__(256) void k_knn(
    const float* __restrict__ h, const float* __restrict__ sq, int* __restrict__ idxout)
{
    int bidx = blockIdx.x;
    int b  = bidx >> 6;
    int n0 = (bidx & 63) << 3;
    int t  = threadIdx.x;

    __shared__ float4 ctr4[8 * 16];
    __shared__ unsigned int keysLDS[8 * 512];
    __shared__ float sqc[8];

    const float* hb = h + (size_t)b * Nn * Hh;
    float* ctr = (float*)ctr4;
    for (int i = t; i < 8 * Hh; i += 256) ctr[i] = hb[(size_t)n0 * Hh + i];
    if (t < 8) sqc[t] = sq[b * Nn + n0 + t];
    __syncthreads();

    {
        int m  = t;
        int m2 = t + 256;
        const float4* hv  = (const float4*)(hb + (size_t)m  * Hh);
        const float4* hv2 = (const float4*)(hb + (size_t)m2 * Hh);
        float dj[8], ej[8];
#pragma unroll
        for (int j = 0; j < 8; ++j) { dj[j] = 0.0f; ej[j] = 0.0f; }
#pragma unroll
        for (int c4 = 0; c4 < 16; ++c4) {
            float4 v  = hv[c4];
            float4 v2 = hv2[c4];
#pragma unroll
            for (int j = 0; j < 8; ++j) {
                float4 cv = ctr4[j * 16 + c4];
                dj[j] += v.x  * cv.x + v.y  * cv.y + v.z  * cv.z + v.w  * cv.w;
                ej[j] += v2.x * cv.x + v2.y * cv.y + v2.z * cv.z + v2.w * cv.w;
            }
        }
        float sm  = sq[b * Nn + m];
        float sm2 = sq[b * Nn + m2];
#pragma unroll
        for (int j = 0; j < 8; ++j) {
            float d = sqc[j] + sm - 2.0f * dj[j];
            unsigned int u = __float_as_uint(d);
            u = ((int)u < 0) ? ~u : (u | 0x80000000u);
            keysLDS[j * 512 + m] = u;

            float d2 = sqc[j] + sm2 - 2.0f * ej[j];
            unsigned int u2 = __float_as_uint(d2);
            u2 = ((int)u2 < 0) ? ~u2 : (u2 | 0x80000000u);
            keysLDS[j * 512 + m2] = u2;
        }
    }
    __syncthreads();

    int wvid = t >> 6, lane = t & 63;
    int j0 = wvid * 2, j1 = wvid * 2 + 1;

    unsigned int k0[8], k1[8];
    int r0[8], r1[8];
    {
        const uint4* kp0 = (const uint4*)&keysLDS[j0 * 512 + (lane << 3)];
        const uint4* kp1 = (const uint4*)&keysLDS[j1 * 512 + (lane << 3)];
        uint4 A = kp0[0], Bq = kp0[1];
        k0[0] = A.x;  k0[1] = A.y;  k0[2] = A.z;  k0[3] = A.w;
        k0[4] = Bq.x; k0[5] = Bq.y; k0[6] = Bq.z; k0[7] = Bq.w;
        uint4 C = kp1[0], D = kp1[1];
        k1[0] = C.x;  k1[1] = C.y;  k1[2] = C.z;  k1[3] = C.w;
        k1[4] = D.x;  k1[5] = D.y;  k1[6] = D.z;  k1[7] = D.w;
    }
#pragma unroll
    for (int q = 0; q < 8; ++q) { r0[q] = q; r1[q] = q; }

#define CE(kk, rr, i, j_) { \
    bool sw = (kk[i] > kk[j_]) || (kk[i] == kk[j_] && rr[i] > rr[j_]); \
    unsigned int tk = sw ? kk[i] : kk[j_]; kk[i] = sw ? kk[j_] : kk[i]; kk[j_] = tk; \
    int tr = sw ? rr[i] : rr[j_]; rr[i] = sw ? rr[j_] : rr[i]; rr[j_] = tr; }
#define SORT8(kk, rr) \
    CE(kk,rr,0,1) CE(kk,rr,2,3) CE(kk,rr,4,5) CE(kk,rr,6,7) \
    CE(kk,rr,0,2) CE(kk,rr,1,3) CE(kk,rr,4,6) CE(kk,rr,5,7) \
    CE(kk,rr,1,2) CE(kk,rr,5,6) \
    CE(kk,rr,0,4) CE(kk,rr,1,5) CE(kk,rr,2,6) CE(kk,rr,3,7) \
    CE(kk,rr,2,4) CE(kk,rr,3,5) \
    CE(kk,rr,1,2) CE(kk,rr,3,4) CE(kk,rr,5,6)

    SORT8(k0, r0)
    SORT8(k1, r1)
#undef SORT8
#undef CE

    int outbase0 = (b * Nn + n0 + j0) * Kk;
    int outbase1 = (b * Nn + n0 + j1) * Kk;

    for (int iter = 0; iter < Kk; ++iter) {
        unsigned int m0 = k0[0];
        unsigned int m1 = k1[0];
#pragma unroll
        for (int sh = 1; sh < 64; sh <<= 1) {
            unsigned int o0 = __shfl_xor(m0, sh, 64);
            unsigned int o1 = __shfl_xor(m1, sh, 64);
            m0 = (o0 < m0) ? o0 : m0;
            m1 = (o1 < m1) ? o1 : m1;
        }
        unsigned long long bal0 = __ballot(k0[0] == m0);
        unsigned long long bal1 = __ballot(k1[0] == m1);
        int w0 = __ffsll(bal0) - 1;
        int w1 = __ffsll(bal1) - 1;
        if (lane == w0) {
            idxout[outbase0 + iter] = (lane << 3) + r0[0];
#pragma unroll
            for (int q = 0; q < 7; ++q) { k0[q] = k0[q + 1]; r0[q] = r0[q + 1]; }
            k0[7] = 0xFFFFFFFFu;
        }
        if (lane == w1) {
            idxout[outbase1 + iter] = (lane << 3) + r1[0];
#pragma unroll
            for (int q = 0; q < 7; ++q) { k1[q] = k1[q + 1]; r1[q] = r1[q + 1]; }
            k1[7] = 0xFFFFFFFFu;
        }
    }
}

// ---------------------------------------------------------------------------
// EdgeConv via MFMA (bf16x3 exact split, 6 products = fp32-equivalent).
// Block: 256 thr (4 waves), G=16 points. Per point: D[k=16][o=64] =
// edge(16x128) @ W^T, edge=[hc ; nb-hc], Kdim=128 in 4 ksteps of 32.
// A-frag: m=lane&15 (k-neighbor), k=quad*8+j. B-frag from row-major W in LDS:
// n=lane&15 (o), k=quad*8+j. C/D: col=lane&15 (o), row=quad*4+reg (k).
// ---------------------------------------------------------------------------
__global__ __launch_bounds__(256, 2) void k_edge(
    const float* __restrict__ h, const int* __restrict__ idx,
    const float* __restrict__ w,
    const float* __restrict__ g, const float* __restrict__ bb_,
    float* __restrict__ hout, float* __restrict__ sqout)
{
    __shared__ float hcF[16 * 72];        // fp32 centers
    __shared__ short hcH[16 * 72];        // center splits (stride 72 shorts)
    __shared__ short hcM[16 * 72];
    __shared__ short hcL[16 * 72];
    __shared__ short wHs[64 * 136];       // W splits, row-major [o][c], stride 136
    __shared__ short wMs[64 * 136];
    __shared__ short wLs[64 * 136];
    __shared__ int   idxS[256];

    int t  = threadIdx.x;
    int p0 = blockIdx.x * 16;
    int b  = p0 >> 9;

    // ---- stage: idx ----
    idxS[t] = idx[p0 * Kk + t];

    // ---- stage: centers (16 pts x 64 ch) + splits ----
    {
        int pl = t >> 4, c4 = t & 15;
        float4 v = *(const float4*)(h + (size_t)(p0 + pl) * Hh + c4 * 4);
        *(float4*)&hcF[pl * 72 + c4 * 4] = v;
        short hs[4], ms[4], ls[4];
        split3(v.x, hs[0], ms[0], ls[0]);
        split3(v.y, hs[1], ms[1], ls[1]);
        split3(v.z, hs[2], ms[2], ls[2]);
        split3(v.w, hs[3], ms[3], ls[3]);
        uint2 uH; uH.x = pk(hs[0], hs[1]); uH.y = pk(hs[2], hs[3]);
        uint2 uM; uM.x = pk(ms[0], ms[1]); uM.y = pk(ms[2], ms[3]);
        uint2 uL; uL.x = pk(ls[0], ls[1]); uL.y = pk(ls[2], ls[3]);
        *(uint2*)&hcH[pl * 72 + c4 * 4] = uH;
        *(uint2*)&hcM[pl * 72 + c4 * 4] = uM;
        *(uint2*)&hcL[pl * 72 + c4 * 4] = uL;
    }

    // ---- stage: W (64 x 128) splits ----
#pragma unroll
    for (int it = 0; it < 8; ++it) {
        int f = it * 256 + t;              // float4 index 0..2047
        int o = f >> 5, c4 = f & 31;
        float4 v = *(const float4*)(w + (size_t)f * 4);
        short hs[4], ms[4], ls[4];
        split3(v.x, hs[0], ms[0], ls[0]);
        split3(v.y, hs[1], ms[1], ls[1]);
        split3(v.z, hs[2], ms[2], ls[2]);
        split3(v.w, hs[3], ms[3], ls[3]);
        uint2 uH; uH.x = pk(hs[0], hs[1]); uH.y = pk(hs[2], hs[3]);
        uint2 uM; uM.x = pk(ms[0], ms[1]); uM.y = pk(ms[2], ms[3]);
        uint2 uL; uL.x = pk(ls[0], ls[1]); uL.y = pk(ls[2], ls[3]);
        *(uint2*)&wHs[o * 136 + c4 * 4] = uH;
        *(uint2*)&wMs[o * 136 + c4 * 4] = uM;
        *(uint2*)&wLs[o * 136 + c4 * 4] = uL;
    }
    __syncthreads();

    int wv   = t >> 6;
    int lane = t & 63;
    int col  = lane & 15;                  // o within N-tile / A-row (k-neighbor)
    int quad = lane >> 4;

    const float inv = rsqrtf(1.0f + EPSf);
    float scv[4], bov[4];
#pragma unroll
    for (int nt = 0; nt < 4; ++nt) {
        int o = nt * 16 + col;
        scv[nt] = g[o] * inv;
        bov[nt] = bb_[o];
    }

    // two point-pairs per wave
    for (int pr = 0; pr < 2; ++pr) {
        bf16x8 AH[2][4], AM[2][4], AL[2][4];

#pragma unroll
        for (int pt2 = 0; pt2 < 2; ++pt2) {
            int pl = (wv << 2) + (pr << 1) + pt2;
            // ks 0/1: hc part (broadcast across rows)
#pragma unroll
            for (int ks = 0; ks < 2; ++ks) {
                int off = pl * 72 + ks * 32 + (quad << 3);
                AH[pt2][ks] = *(bf16x8*)&hcH[off];
                AM[pt2][ks] = *(bf16x8*)&hcM[off];
                AL[pt2][ks] = *(bf16x8*)&hcL[off];
            }
            // ks 2/3: nb - hc (row = neighbor k = col)
            int j = idxS[(pl << 4) + col];
            const float* nbr = h + ((size_t)(b << 9) + j) * Hh;
#pragma unroll
            for (int ks = 2; ks < 4; ++ks) {
                int c0 = ((ks - 2) << 5) + (quad << 3);
                float4 n0 = *(const float4*)(nbr + c0);
                float4 n1 = *(const float4*)(nbr + c0 + 4);
                float4 ca = *(float4*)&hcF[pl * 72 + c0];
                float4 cb = *(float4*)&hcF[pl * 72 + c0 + 4];
                float d[8] = { n0.x - ca.x, n0.y - ca.y, n0.z - ca.z, n0.w - ca.w,
                               n1.x - cb.x, n1.y - cb.y, n1.z - cb.z, n1.w - cb.w };
                bf16x8 h8, m8, l8;
#pragma unroll
                for (int e = 0; e < 8; ++e) {
                    short hs, ms, ls;
                    split3(d[e], hs, ms, ls);
                    h8[e] = hs; m8[e] = ms; l8[e] = ls;
                }
                AH[pt2][ks] = h8; AM[pt2][ks] = m8; AL[pt2][ks] = l8;
            }
        }

        f32x4 acc[2][4];
#pragma unroll
        for (int pt2 = 0; pt2 < 2; ++pt2)
#pragma unroll
            for (int nt = 0; nt < 4; ++nt)
                acc[pt2][nt] = (f32x4){0.0f, 0.0f, 0.0f, 0.0f};

#pragma unroll
        for (int nt = 0; nt < 4; ++nt) {
#pragma unroll
            for (int ks = 0; ks < 4; ++ks) {
                int boff = (nt * 16 + col) * 136 + ks * 32 + (quad << 3);
                bf16x8 BH = *(bf16x8*)&wHs[boff];
                bf16x8 BM = *(bf16x8*)&wMs[boff];
                bf16x8 BL = *(bf16x8*)&wLs[boff];
#pragma unroll
                for (int pt2 = 0; pt2 < 2; ++pt2) {
                    f32x4 a = acc[pt2][nt];
                    a = __builtin_amdgcn_mfma_f32_16x16x32_bf16(AL[pt2][ks], BH, a, 0, 0, 0);
                    a = __builtin_amdgcn_mfma_f32_16x16x32_bf16(AM[pt2][ks], BM, a, 0, 0, 0);
                    a = __builtin_amdgcn_mfma_f32_16x16x32_bf16(AH[pt2][ks], BL, a, 0, 0, 0);
                    a = __builtin_amdgcn_mfma_f32_16x16x32_bf16(AM[pt2][ks], BH, a, 0, 0, 0);
                    a = __builtin_amdgcn_mfma_f32_16x16x32_bf16(AH[pt2][ks], BM, a, 0, 0, 0);
                    a = __builtin_amdgcn_mfma_f32_16x16x32_bf16(AH[pt2][ks], BH, a, 0, 0, 0);
                    acc[pt2][nt] = a;
                }
            }
        }

        // epilogue: bn per-k, max over k (4 regs + cross-quad), relu
#pragma unroll
        for (int pt2 = 0; pt2 < 2; ++pt2) {
            int pl = (wv << 2) + (pr << 1) + pt2;
            int pglob = p0 + pl;
            float res[4];
#pragma unroll
            for (int nt = 0; nt < 4; ++nt) {
                f32x4 a = acc[pt2][nt];
                float sc = scv[nt], bo = bov[nt];
                float v0 = fmaf(a[0], sc, bo);
                float v1 = fmaf(a[1], sc, bo);
                float v2 = fmaf(a[2], sc, bo);
                float v3 = fmaf(a[3], sc, bo);
                float vm = fmaxf(fmaxf(v0, v1), fmaxf(v2, v3));
                vm = fmaxf(vm, __shfl_xor(vm, 16));
                vm = fmaxf(vm, __shfl_xor(vm, 32));
                res[nt] = fmaxf(vm, 0.0f);
            }
            float rv = (lane < 16) ? res[0] : (lane < 32) ? res[1]
                     : (lane < 48) ? res[2] : res[3];
            hout[(size_t)pglob * Hh + lane] = rv;

            float s = res[0] * res[0] + res[1] * res[1]
                    + res[2] * res[2] + res[3] * res[3];
            s += __shfl_xor(s, 1);
            s += __shfl_xor(s, 2);
            s += __shfl_xor(s, 4);
            s += __shfl_xor(s, 8);
            if (lane == 0) sqout[pglob] = s;
        }
    }
}

// ---------------------------------------------------------------------------
// head (unchanged)
// ---------------------------------------------------------------------------
__global__ __launch_bounds__(256) void k_head(
    const float* __restrict__ h,
    const float* __restrict__ w1, const float* __restrict__ g1, const float* __restrict__ b1,
    const float* __restrict__ w2, const float* __restrict__ b2,
    float* __restrict__ out)
{
    __shared__ float hcS[4][64];
    int t = threadIdx.x;
    int grp = t >> 6, o = t & 63;
    int p = blockIdx.x * 4 + grp;

    hcS[grp][o] = h[(size_t)p * Hh + o];
    __syncthreads();

    const float inv = rsqrtf(1.0f + EPSf);
    float acc = 0.0f;
#pragma unroll 8
    for (int c = 0; c < Hh; ++c)
        acc = fmaf(w1[o * Hh + c], hcS[grp][c], acc);
    acc = fmaxf(fmaf(acc, g1[o] * inv, b1[o]), 0.0f);

    float v = acc * w2[o];
#pragma unroll
    for (int off = 32; off > 0; off >>= 1) v += __shfl_down(v, off, 64);
    if (o == 0) out[p] = v + b2[0];
}

// ---------------------------------------------------------------------------
extern "C" void kernel_launch(void* const* d_in, const int* in_sizes, int n_in,
                              void* d_out, int out_size, void* d_ws, size_t ws_size,
                              hipStream_t stream)
{
    const float* x    = (const float*)d_in[0];
    const float* w_t1 = (const float*)d_in[1];
    const float* g_t1 = (const float*)d_in[2];
    const float* b_t1 = (const float*)d_in[3];
    const float* w_t2 = (const float*)d_in[4];
    const float* g_t2 = (const float*)d_in[5];
    const float* b_t2 = (const float*)d_in[6];
    const float* w_nb = (const float*)d_in[7];
    const float* g_nb = (const float*)d_in[8];
    const float* b_nb = (const float*)d_in[9];
    const float* w_s1 = (const float*)d_in[10];
    const float* g_s1 = (const float*)d_in[11];
    const float* b_s1 = (const float*)d_in[12];
    const float* w_s2 = (const float*)d_in[13];
    const float* b_s2 = (const float*)d_in[14];
    float* out = (float*)d_out;

    float* hA  = (float*)d_ws;
    float* hB  = hA + (size_t)Bn * Nn * Hh;
    float* sq  = hB + (size_t)Bn * Nn * Hh;
    int*   idx = (int*)(sq + (size_t)Bn * Nn);

    k_t12<<<Bn * Nn / 4, 256, 0, stream>>>(x, w_t1, g_t1, b_t1, w_t2, g_t2, b_t2, hA, sq);

    const float* hin = hA;
    float* hout = hB;
    for (int r = 0; r < Rr; ++r) {
        k_knn<<<Bn * (Nn / 8), 256, 0, stream>>>(hin, sq, idx);
        k_edge<<<Bn * Nn / 16, 256, 0, stream>>>(hin, idx,
            w_nb + (size_t)r * Hh * 2 * Hh, g_nb + r * Hh, b_nb + r * Hh, hout, sq);
        const float* tmp = hout; hout = (float*)hin; hin = tmp;
    }
    k_head<<<Bn * Nn / 4, 256, 0, stream>>>(hin, w_s1, g_s1, b_s1, w_s2, b_s2, out);
}

// Round 5
// 887.082 us; speedup vs baseline: 3.3471x; 1.0385x over previous
//
#include <hip/hip_runtime.h>
#include <math.h>

#define Bn 128
#define Nn 512
#define Cc 7
#define Hh 64
#define Kk 16
#define Rr 2
#define EPSf 1e-5f

typedef __attribute__((ext_vector_type(8))) short bf16x8;
typedef __attribute__((ext_vector_type(4))) float f32x4;

#define PLN ((size_t)4194304)   // elements per h-split plane (B*N*H)

// exact truncation split: a = hi + mid + lo + r, |r| <= 2^-24 |a|
__device__ __forceinline__ void split3(float a, short &hs, short &ms, short &ls) {
    unsigned u  = __float_as_uint(a);
    unsigned hu = u & 0xFFFF0000u;
    float r1 = a - __uint_as_float(hu);
    unsigned mu = __float_as_uint(r1) & 0xFFFF0000u;
    float r2 = r1 - __uint_as_float(mu);
    unsigned lu = __float_as_uint(r2) & 0xFFFF0000u;
    hs = (short)(hu >> 16); ms = (short)(mu >> 16); ls = (short)(lu >> 16);
}

#define MFMA6(acc, AH, AM, AL, BH, BM, BL) \
    acc = __builtin_amdgcn_mfma_f32_16x16x32_bf16(AL, BH, acc, 0, 0, 0); \
    acc = __builtin_amdgcn_mfma_f32_16x16x32_bf16(AM, BM, acc, 0, 0, 0); \
    acc = __builtin_amdgcn_mfma_f32_16x16x32_bf16(AH, BL, acc, 0, 0, 0); \
    acc = __builtin_amdgcn_mfma_f32_16x16x32_bf16(AM, BH, acc, 0, 0, 0); \
    acc = __builtin_amdgcn_mfma_f32_16x16x32_bf16(AH, BM, acc, 0, 0, 0); \
    acc = __builtin_amdgcn_mfma_f32_16x16x32_bf16(AH, BH, acc, 0, 0, 0);

// ---------------------------------------------------------------------------
// prep: split W per round into Wd (bf16x3) and Wc-Wd (bf16x3) planes.
// wS layout per round: [wdH, wdM, wdL, wcdH, wcdM, wcdL], each 64x64 row-major
// ---------------------------------------------------------------------------
__global__ void k_prep(const float* __restrict__ w_nb, short* __restrict__ wS)
{
    int i = blockIdx.x * 256 + threadIdx.x;     // 0 .. 2*64*64-1
    int r = i >> 12, oc = i & 4095;
    int o = oc >> 6, c = oc & 63;
    const float* wr = w_nb + (size_t)r * Hh * 2 * Hh + (size_t)o * 2 * Hh;
    float wc = wr[c], wd = wr[Hh + c];
    short* base = wS + (size_t)r * 6 * 4096;
    short h_, m_, l_;
    split3(wd, h_, m_, l_);
    base[0 * 4096 + oc] = h_; base[1 * 4096 + oc] = m_; base[2 * 4096 + oc] = l_;
    split3(wc - wd, h_, m_, l_);
    base[3 * 4096 + oc] = h_; base[4 * 4096 + oc] = m_; base[5 * 4096 + oc] = l_;
}

// ---------------------------------------------------------------------------
// t1 + t2 fused (h values bit-identical to prior rounds) + split-plane output
// ---------------------------------------------------------------------------
__global__ __launch_bounds__(256) void k_t12(
    const float* __restrict__ x,
    const float* __restrict__ w1, const float* __restrict__ g1, const float* __restrict__ b1,
    const float* __restrict__ w2, const float* __restrict__ g2, const float* __restrict__ b2,
    float* __restrict__ h, short* __restrict__ hS, float* __restrict__ sq)
{
    int t = threadIdx.x;
    int grp = t >> 6, o = t & 63;
    int p = blockIdx.x * 4 + grp;
    int b = p >> 9, n = p & 511;

    __shared__ float h1s[4][64];
    const float inv = rsqrtf(1.0f + EPSf);

    float acc = 0.0f;
#pragma unroll
    for (int c = 0; c < Cc; ++c)
        acc = fmaf(w1[o * Cc + c], x[(b * Cc + c) * Nn + n], acc);
    acc = fmaf(acc, g1[o] * inv, b1[o]);
    acc = fmaxf(acc, 0.0f);
    h1s[grp][o] = acc;
    __syncthreads();

    float a2 = 0.0f;
#pragma unroll 8
    for (int c = 0; c < Hh; ++c)
        a2 = fmaf(w2[o * Hh + c], h1s[grp][c], a2);
    a2 = fmaf(a2, g2[o] * inv, b2[o]);
    a2 = fmaxf(a2, 0.0f);
    h[(size_t)p * Hh + o] = a2;
    short hs_, ms_, ls_;
    split3(a2, hs_, ms_, ls_);
    hS[0 * PLN + (size_t)p * Hh + o] = hs_;
    hS[1 * PLN + (size_t)p * Hh + o] = ms_;
    hS[2 * PLN + (size_t)p * Hh + o] = ls_;

    float s = a2 * a2;
#pragma unroll
    for (int off = 32; off > 0; off >>= 1) s += __shfl_down(s, off, 64);
    if (o == 0) sq[p] = s;
}

// ---------------------------------------------------------------------------
// kNN: 128 threads, 4 points/thread (128 FMA per 8 LDS reads), 8 centers.
// Distance expression per (point,center) textually identical to round 2-4.
// Selection: 2 waves x 2 pair-iterations (interleaved dual chains).
// ---------------------------------------------------------------------------
__global__ __launch_bounds__(128) void k_knn(
    const float* __restrict__ h, const float* __restrict__ sq, int* __restrict__ idxout)
{
    int bidx = blockIdx.x;
    int b  = bidx >> 6;
    int n0 = (bidx & 63) << 3;
    int t  = threadIdx.x;

    __shared__ float4 ctr4[8 * 16];
    __shared__ unsigned int keysLDS[8 * 512];
    __shared__ float sqc[8];

    const float* hb = h + (size_t)b * Nn * Hh;
    float* ctr = (float*)ctr4;
    for (int i = t; i < 8 * Hh; i += 128) ctr[i] = hb[(size_t)n0 * Hh + i];
    if (t < 8) sqc[t] = sq[b * Nn + n0 + t];
    __syncthreads();

    {
        const float4* hv0 = (const float4*)(hb + (size_t)(t)       * Hh);
        const float4* hv1 = (const float4*)(hb + (size_t)(t + 128) * Hh);
        const float4* hv2 = (const float4*)(hb + (size_t)(t + 256) * Hh);
        const float4* hv3 = (const float4*)(hb + (size_t)(t + 384) * Hh);
        float d0[8], d1[8], d2[8], d3[8];
#pragma unroll
        for (int j = 0; j < 8; ++j) { d0[j]=0.f; d1[j]=0.f; d2[j]=0.f; d3[j]=0.f; }
#pragma unroll
        for (int c4 = 0; c4 < 16; ++c4) {
            float4 v0 = hv0[c4], v1 = hv1[c4], v2 = hv2[c4], v3 = hv3[c4];
#pragma unroll
            for (int j = 0; j < 8; ++j) {
                float4 cv = ctr4[j * 16 + c4];
                d0[j] += v0.x * cv.x + v0.y * cv.y + v0.z * cv.z + v0.w * cv.w;
                d1[j] += v1.x * cv.x + v1.y * cv.y + v1.z * cv.z + v1.w * cv.w;
                d2[j] += v2.x * cv.x + v2.y * cv.y + v2.z * cv.z + v2.w * cv.w;
                d3[j] += v3.x * cv.x + v3.y * cv.y + v3.z * cv.z + v3.w * cv.w;
            }
        }
        float s0 = sq[b * Nn + t];
        float s1 = sq[b * Nn + t + 128];
        float s2 = sq[b * Nn + t + 256];
        float s3 = sq[b * Nn + t + 384];
#pragma unroll
        for (int j = 0; j < 8; ++j) {
            float d; unsigned int u;
            d = sqc[j] + s0 - 2.0f * d0[j];
            u = __float_as_uint(d); u = ((int)u < 0) ? ~u : (u | 0x80000000u);
            keysLDS[j * 512 + t] = u;
            d = sqc[j] + s1 - 2.0f * d1[j];
            u = __float_as_uint(d); u = ((int)u < 0) ? ~u : (u | 0x80000000u);
            keysLDS[j * 512 + t + 128] = u;
            d = sqc[j] + s2 - 2.0f * d2[j];
            u = __float_as_uint(d); u = ((int)u < 0) ? ~u : (u | 0x80000000u);
            keysLDS[j * 512 + t + 256] = u;
            d = sqc[j] + s3 - 2.0f * d3[j];
            u = __float_as_uint(d); u = ((int)u < 0) ? ~u : (u | 0x80000000u);
            keysLDS[j * 512 + t + 384] = u;
        }
    }
    __syncthreads();

    int wvid = t >> 6, lane = t & 63;

    for (int pr = 0; pr < 2; ++pr) {
        int j0 = wvid * 4 + pr * 2, j1 = j0 + 1;

        unsigned int k0[8], k1[8];
        int r0[8], r1[8];
        {
            const uint4* kp0 = (const uint4*)&keysLDS[j0 * 512 + (lane << 3)];
            const uint4* kp1 = (const uint4*)&keysLDS[j1 * 512 + (lane << 3)];
            uint4 A = kp0[0], Bq = kp0[1];
            k0[0] = A.x;  k0[1] = A.y;  k0[2] = A.z;  k0[3] = A.w;
            k0[4] = Bq.x; k0[5] = Bq.y; k0[6] = Bq.z; k0[7] = Bq.w;
            uint4 C = kp1[0], D = kp1[1];
            k1[0] = C.x;  k1[1] = C.y;  k1[2] = C.z;  k1[3] = C.w;
            k1[4] = D.x;  k1[5] = D.y;  k1[6] = D.z;  k1[7] = D.w;
        }
#pragma unroll
        for (int q = 0; q < 8; ++q) { r0[q] = q; r1[q] = q; }

#define CE(kk, rr, i, j_) { \
    bool sw = (kk[i] > kk[j_]) || (kk[i] == kk[j_] && rr[i] > rr[j_]); \
    unsigned int tk = sw ? kk[i] : kk[j_]; kk[i] = sw ? kk[j_] : kk[i]; kk[j_] = tk; \
    int tr = sw ? rr[i] : rr[j_]; rr[i] = sw ? rr[j_] : rr[i]; rr[j_] = tr; }
#define SORT8(kk, rr) \
    CE(kk,rr,0,1) CE(kk,rr,2,3) CE(kk,rr,4,5) CE(kk,rr,6,7) \
    CE(kk,rr,0,2) CE(kk,rr,1,3) CE(kk,rr,4,6) CE(kk,rr,5,7) \
    CE(kk,rr,1,2) CE(kk,rr,5,6) \
    CE(kk,rr,0,4) CE(kk,rr,1,5) CE(kk,rr,2,6) CE(kk,rr,3,7) \
    CE(kk,rr,2,4) CE(kk,rr,3,5) \
    CE(kk,rr,1,2) CE(kk,rr,3,4) CE(kk,rr,5,6)

        SORT8(k0, r0)
        SORT8(k1, r1)
#undef SORT8
#undef CE

        int outbase0 = (b * Nn + n0 + j0) * Kk;
        int outbase1 = (b * Nn + n0 + j1) * Kk;

        for (int iter = 0; iter < Kk; ++iter) {
            unsigned int m0 = k0[0];
            unsigned int m1 = k1[0];
#pragma unroll
            for (int sh = 1; sh < 64; sh <<= 1) {
                unsigned int o0 = __shfl_xor(m0, sh, 64);
                unsigned int o1 = __shfl_xor(m1, sh, 64);
                m0 = (o0 < m0) ? o0 : m0;
                m1 = (o1 < m1) ? o1 : m1;
            }
            unsigned long long bal0 = __ballot(k0[0] == m0);
            unsigned long long bal1 = __ballot(k1[0] == m1);
            int w0 = __ffsll(bal0) - 1;
            int w1 = __ffsll(bal1) - 1;
            if (lane == w0) {
                idxout[outbase0 + iter] = (lane << 3) + r0[0];
#pragma unroll
                for (int q = 0; q < 7; ++q) { k0[q] = k0[q + 1]; r0[q] = r0[q + 1]; }
                k0[7] = 0xFFFFFFFFu;
            }
            if (lane == w1) {
                idxout[outbase1 + iter] = (lane << 3) + r1[0];
#pragma unroll
                for (int q = 0; q < 7; ++q) { k1[q] = k1[q + 1]; r1[q] = r1[q + 1]; }
                k1[7] = 0xFFFFFFFFu;
            }
        }
    }
}

// ---------------------------------------------------------------------------
// EdgeConv via MFMA, base/delta decomposition:
//   m = (Wc-Wd)@hc  (base, 16x64 per block, one nt-tile per wave)
//     + Wd@nb       (delta, K=64 per point)
// A-fragments gathered directly from precomputed bf16x3 h planes — no split3
// in the hot loop, low register pressure (no spills).
// ---------------------------------------------------------------------------
__global__ __launch_bounds__(256) void k_edge(
    const float* __restrict__ h, const short* __restrict__ hS,
    const int* __restrict__ idx,
    const short* __restrict__ wS,
    const float* __restrict__ g, const float* __restrict__ bb_,
    float* __restrict__ hout, short* __restrict__ hSout, float* __restrict__ sqout)
{
    __shared__ short wdS[3][64 * 72];
    __shared__ short wcdS[3][64 * 72];
    __shared__ float baseS[16 * 68];
    __shared__ int   idxS[256];

    int t  = threadIdx.x;
    int p0 = blockIdx.x * 16;
    int b  = p0 >> 9;

    idxS[t] = idx[p0 * Kk + t];
#pragma unroll
    for (int it = 0; it < 12; ++it) {
        int f = it * 256 + t;              // uint4 index 0..3071
        int plane = f >> 9;                // 0..5
        int i8 = f & 511;
        int o = i8 >> 3, c8 = i8 & 7;
        uint4 v = ((const uint4*)(wS + (size_t)plane * 4096))[i8];
        short* dst = (plane < 3) ? &wdS[plane][0] : &wcdS[plane - 3][0];
        *(uint4*)&dst[o * 72 + c8 * 8] = v;
    }
    __syncthreads();

    int wv = t >> 6, lane = t & 63, col = lane & 15, quad = lane >> 4;

    // ---- base phase: wave wv computes nt=wv tile of base[16 pts][16 o] ----
    {
        f32x4 bacc = (f32x4){0.f, 0.f, 0.f, 0.f};
        const short* hrow = hS + (size_t)(p0 + col) * Hh;
#pragma unroll
        for (int ks = 0; ks < 2; ++ks) {
            int aoff = ks * 32 + quad * 8;
            bf16x8 AH = *(const bf16x8*)(hrow + 0 * PLN + aoff);
            bf16x8 AM = *(const bf16x8*)(hrow + 1 * PLN + aoff);
            bf16x8 AL = *(const bf16x8*)(hrow + 2 * PLN + aoff);
            int boff = (wv * 16 + col) * 72 + aoff;
            bf16x8 BH = *(bf16x8*)&wcdS[0][boff];
            bf16x8 BM = *(bf16x8*)&wcdS[1][boff];
            bf16x8 BL = *(bf16x8*)&wcdS[2][boff];
            MFMA6(bacc, AH, AM, AL, BH, BM, BL)
        }
#pragma unroll
        for (int r_ = 0; r_ < 4; ++r_)
            baseS[(quad * 4 + r_) * 68 + wv * 16 + col] = bacc[r_];
    }
    __syncthreads();

    const float inv = rsqrtf(1.0f + EPSf);
    float scv[4], bov[4];
#pragma unroll
    for (int nt = 0; nt < 4; ++nt) {
        scv[nt] = g[nt * 16 + col] * inv;
        bov[nt] = bb_[nt * 16 + col];
    }

    for (int pr = 0; pr < 2; ++pr) {
        bf16x8 A[2][2][3];
#pragma unroll
        for (int pt2 = 0; pt2 < 2; ++pt2) {
            int pl = wv * 4 + pr * 2 + pt2;
            int j = idxS[pl * 16 + col];
            const short* nrow = hS + ((size_t)(b * Nn) + j) * Hh;
#pragma unroll
            for (int ks = 0; ks < 2; ++ks) {
                int aoff = ks * 32 + quad * 8;
                A[pt2][ks][0] = *(const bf16x8*)(nrow + 0 * PLN + aoff);
                A[pt2][ks][1] = *(const bf16x8*)(nrow + 1 * PLN + aoff);
                A[pt2][ks][2] = *(const bf16x8*)(nrow + 2 * PLN + aoff);
            }
        }

        f32x4 acc[2][4];
#pragma unroll
        for (int pt2 = 0; pt2 < 2; ++pt2)
#pragma unroll
            for (int nt = 0; nt < 4; ++nt)
                acc[pt2][nt] = (f32x4){0.f, 0.f, 0.f, 0.f};

#pragma unroll
        for (int ks = 0; ks < 2; ++ks)
#pragma unroll
            for (int nt = 0; nt < 4; ++nt) {
                int boff = (nt * 16 + col) * 72 + ks * 32 + quad * 8;
                bf16x8 BH = *(bf16x8*)&wdS[0][boff];
                bf16x8 BM = *(bf16x8*)&wdS[1][boff];
                bf16x8 BL = *(bf16x8*)&wdS[2][boff];
#pragma unroll
                for (int pt2 = 0; pt2 < 2; ++pt2) {
                    f32x4 a = acc[pt2][nt];
                    MFMA6(a, A[pt2][ks][0], A[pt2][ks][1], A[pt2][ks][2], BH, BM, BL)
                    acc[pt2][nt] = a;
                }
            }

        // epilogue: m = base + delta; bn per-k; max over k; relu
#pragma unroll
        for (int pt2 = 0; pt2 < 2; ++pt2) {
            int pl = wv * 4 + pr * 2 + pt2;
            int pglob = p0 + pl;
            float res[4];
#pragma unroll
            for (int nt = 0; nt < 4; ++nt) {
                float base = baseS[pl * 68 + nt * 16 + col];
                f32x4 a = acc[pt2][nt];
                float v0 = fmaf(base + a[0], scv[nt], bov[nt]);
                float v1 = fmaf(base + a[1], scv[nt], bov[nt]);
                float v2 = fmaf(base + a[2], scv[nt], bov[nt]);
                float v3 = fmaf(base + a[3], scv[nt], bov[nt]);
                float vm = fmaxf(fmaxf(v0, v1), fmaxf(v2, v3));
                vm = fmaxf(vm, __shfl_xor(vm, 16));
                vm = fmaxf(vm, __shfl_xor(vm, 32));
                res[nt] = fmaxf(vm, 0.0f);
            }
            float rv = res[quad];
            hout[(size_t)pglob * Hh + lane] = rv;
            short hs_, ms_, ls_;
            split3(rv, hs_, ms_, ls_);
            hSout[0 * PLN + (size_t)pglob * Hh + lane] = hs_;
            hSout[1 * PLN + (size_t)pglob * Hh + lane] = ms_;
            hSout[2 * PLN + (size_t)pglob * Hh + lane] = ls_;

            float s = res[0] * res[0] + res[1] * res[1]
                    + res[2] * res[2] + res[3] * res[3];
            s += __shfl_xor(s, 1);
            s += __shfl_xor(s, 2);
            s += __shfl_xor(s, 4);
            s += __shfl_xor(s, 8);
            if (lane == 0) sqout[pglob] = s;
        }
    }
}

// ---------------------------------------------------------------------------
// head (unchanged)
// ---------------------------------------------------------------------------
__global__ __launch_bounds__(256) void k_head(
    const float* __restrict__ h,
    const float* __restrict__ w1, const float* __restrict__ g1, const float* __restrict__ b1,
    const float* __restrict__ w2, const float* __restrict__ b2,
    float* __restrict__ out)
{
    __shared__ float hcS[4][64];
    int t = threadIdx.x;
    int grp = t >> 6, o = t & 63;
    int p = blockIdx.x * 4 + grp;

    hcS[grp][o] = h[(size_t)p * Hh + o];
    __syncthreads();

    const float inv = rsqrtf(1.0f + EPSf);
    float acc = 0.0f;
#pragma unroll 8
    for (int c = 0; c < Hh; ++c)
        acc = fmaf(w1[o * Hh + c], hcS[grp][c], acc);
    acc = fmaxf(fmaf(acc, g1[o] * inv, b1[o]), 0.0f);

    float v = acc * w2[o];
#pragma unroll
    for (int off = 32; off > 0; off >>= 1) v += __shfl_down(v, off, 64);
    if (o == 0) out[p] = v + b2[0];
}

// ---------------------------------------------------------------------------
extern "C" void kernel_launch(void* const* d_in, const int* in_sizes, int n_in,
                              void* d_out, int out_size, void* d_ws, size_t ws_size,
                              hipStream_t stream)
{
    const float* x    = (const float*)d_in[0];
    const float* w_t1 = (const float*)d_in[1];
    const float* g_t1 = (const float*)d_in[2];
    const float* b_t1 = (const float*)d_in[3];
    const float* w_t2 = (const float*)d_in[4];
    const float* g_t2 = (const float*)d_in[5];
    const float* b_t2 = (const float*)d_in[6];
    const float* w_nb = (const float*)d_in[7];
    const float* g_nb = (const float*)d_in[8];
    const float* b_nb = (const float*)d_in[9];
    const float* w_s1 = (const float*)d_in[10];
    const float* g_s1 = (const float*)d_in[11];
    const float* b_s1 = (const float*)d_in[12];
    const float* w_s2 = (const float*)d_in[13];
    const float* b_s2 = (const float*)d_in[14];
    float* out = (float*)d_out;

    float* hA  = (float*)d_ws;
    float* hB  = hA + PLN;
    float* sq  = hB + PLN;
    int*   idx = (int*)(sq + (size_t)Bn * Nn);
    short* hSa = (short*)(idx + (size_t)Bn * Nn * Kk);
    short* hSb = hSa + 3 * PLN;
    short* wS  = hSb + 3 * PLN;

    k_prep<<<32, 256, 0, stream>>>(w_nb, wS);
    k_t12<<<Bn * Nn / 4, 256, 0, stream>>>(x, w_t1, g_t1, b_t1, w_t2, g_t2, b_t2,
                                           hA, hSa, sq);

    const float* hin = hA;
    float* hout = hB;
    const short* hSin = hSa;
    short* hSout = hSb;
    for (int r = 0; r < Rr; ++r) {
        k_knn<<<Bn * (Nn / 8), 128, 0, stream>>>(hin, sq, idx);
        k_edge<<<Bn * Nn / 16, 256, 0, stream>>>(hin, hSin, idx,
            wS + (size_t)r * 6 * 4096, g_nb + r * Hh, b_nb + r * Hh,
            hout, hSout, sq);
        const float* tf = hout; hout = (float*)hin; hin = tf;
        const short* ts = hSout; hSout = (short*)hSin; hSin = ts;
    }
    k_head<<<Bn * Nn / 4, 256, 0, stream>>>(hin, w_s1, g_s1, b_s1, w_s2, b_s2, out);
}